// Round 1
// 577.908 us; speedup vs baseline: 1.1684x; 1.1684x over previous
//
#include <hip/hip_runtime.h>

#define B_ 8
#define N_ 1024
#define C_ 768
#define H_ 12
#define D_ 64
#define SCALE_ 0.125f

typedef _Float16 v8h __attribute__((ext_vector_type(8)));
typedef float v4f __attribute__((ext_vector_type(4)));

__device__ __forceinline__ void gload_lds16(const void* g, void* l) {
    __builtin_amdgcn_global_load_lds((const __attribute__((address_space(1))) void*)g,
                                     (__attribute__((address_space(3))) void*)l, 16, 0, 0);
}

// ---------------------------------------------------------------------------
// cast fp32 -> fp16, 8 elems/thread
// ---------------------------------------------------------------------------
__global__ __launch_bounds__(256) void cast_f2h(const float* __restrict__ src,
                                                _Float16* __restrict__ dst, int n8) {
    const int i = blockIdx.x * 256 + threadIdx.x;
    if (i < n8) {
        const v4f a = *(const v4f*)&src[(size_t)i * 8];
        const v4f b = *(const v4f*)&src[(size_t)i * 8 + 4];
        v8h o;
        o[0] = (_Float16)a[0]; o[1] = (_Float16)a[1]; o[2] = (_Float16)a[2]; o[3] = (_Float16)a[3];
        o[4] = (_Float16)b[0]; o[5] = (_Float16)b[1]; o[6] = (_Float16)b[2]; o[7] = (_Float16)b[3];
        *(v8h*)&dst[(size_t)i * 8] = o;
    }
}

// ---------------------------------------------------------------------------
// K1: qkv = xh[8192,768] @ wqh[2304,768]^T via MFMA. 128x128 tile, BK=32,
// double-buffered LDS, ONE barrier per K-step (stage issued at top of iter,
// drained by compiler vmcnt(0) at the barrier -> latency hides under MFMA).
// Epilogue scatters q,k [B,H,N,D] and v transposed [B,H,D,N], fp16.
// ---------------------------------------------------------------------------
__global__ __launch_bounds__(256) void gemm_qkv(const _Float16* __restrict__ X,
                                                const _Float16* __restrict__ W,
                                                _Float16* __restrict__ qh,
                                                _Float16* __restrict__ kh,
                                                _Float16* __restrict__ vth) {
    __shared__ _Float16 As[2 * 128 * 32];
    __shared__ _Float16 Bs[2 * 128 * 32];
    const int t = threadIdx.x;
    const int w = t >> 6, l = t & 63;
    const int q4 = l >> 4, c0 = l & 15;
    const int wm = w & 1, wn = w >> 1;
    const int m0 = blockIdx.x * 128, n0 = blockIdx.y * 128;
    const int sc8 = (t & 3) * 8;
    const int srow = t >> 2;
    v4f acc[4][4] = {};
    // prologue: stage chunk 0 into buf 0
    #pragma unroll
    for (int i = 0; i < 2; ++i) {
        const int row = i * 64 + srow;
        gload_lds16(&X[(size_t)(m0 + row) * C_ + sc8], &As[(i * 256 + t) * 8]);
        gload_lds16(&W[(size_t)(n0 + row) * C_ + sc8], &Bs[(i * 256 + t) * 8]);
    }
    __syncthreads();
    int cb = 0;
    for (int k0 = 0; k0 < C_; k0 += 32, cb ^= 1) {
        if (k0 + 32 < C_) {
            const int nb = cb ^ 1;
            #pragma unroll
            for (int i = 0; i < 2; ++i) {
                const int row = i * 64 + srow;
                gload_lds16(&X[(size_t)(m0 + row) * C_ + k0 + 32 + sc8],
                            &As[(nb * 512 + i * 256 + t) * 8]);
                gload_lds16(&W[(size_t)(n0 + row) * C_ + k0 + 32 + sc8],
                            &Bs[(nb * 512 + i * 256 + t) * 8]);
            }
        }
        v8h a[4], b[4];
        #pragma unroll
        for (int mi = 0; mi < 4; ++mi)
            a[mi] = *(const v8h*)&As[cb * 4096 + (wm * 64 + mi * 16 + c0) * 32 + q4 * 8];
        #pragma unroll
        for (int ni = 0; ni < 4; ++ni)
            b[ni] = *(const v8h*)&Bs[cb * 4096 + (wn * 64 + ni * 16 + c0) * 32 + q4 * 8];
        #pragma unroll
        for (int mi = 0; mi < 4; ++mi)
            #pragma unroll
            for (int ni = 0; ni < 4; ++ni)
                acc[mi][ni] = __builtin_amdgcn_mfma_f32_16x16x32_f16(a[mi], b[ni], acc[mi][ni], 0, 0, 0);
        __syncthreads();
    }
    const int which = n0 / C_;       // block fully inside one of q/k/v
    const int nbase = n0 % C_;
    #pragma unroll
    for (int ni = 0; ni < 4; ++ni) {
        const int n = nbase + wn * 64 + ni * 16 + c0;
        const int h = n >> 6, d = n & 63;
        #pragma unroll
        for (int mi = 0; mi < 4; ++mi) {
            #pragma unroll
            for (int r = 0; r < 4; ++r) {
                const int m = m0 + wm * 64 + mi * 16 + q4 * 4 + r;
                const int b = m >> 10, nn = m & 1023;
                const _Float16 val = (_Float16)acc[mi][ni][r];
                if (which == 0)
                    qh[((size_t)(b * H_ + h) * N_ + nn) * D_ + d] = val;
                else if (which == 1)
                    kh[((size_t)(b * H_ + h) * N_ + nn) * D_ + d] = val;
                else
                    vth[((size_t)(b * H_ + h) * D_ + d) * N_ + nn] = val;
            }
        }
    }
}

// ---------------------------------------------------------------------------
// K2: fused attention. Block = 32 q-rows x one (b,h). Grid (32, 96),
// 512 threads = 8 waves as 2 row-groups (wg) x 4 col-groups (wl).
// QK^T over 16 K-chunks of 64 rows, double-buffered, 1 barrier/chunk with
// stage-at-top (T3 2-phase). fp32 softmax (shfl16 + LDS x-wave). PV over 16
// V-slabs of 64 cols, double-buffered Vt AND Ps; V-slab-0 staged under the
// softmax exp pass; attn stores nontemporal (never re-read; protect L2).
// ---------------------------------------------------------------------------
__global__ __launch_bounds__(512, 4) void attn_fused(const _Float16* __restrict__ qh,
                                                     const _Float16* __restrict__ kh,
                                                     const _Float16* __restrict__ vth,
                                                     float* __restrict__ attn,
                                                     _Float16* __restrict__ oah) {
    __shared__ _Float16 Qs[2 * 32 * 32];        // [piece][row][32]
    __shared__ _Float16 Ks[2 * 2 * 64 * 32];    // [buf][piece][row][32]
    __shared__ _Float16 Vt[2 * 2 * 64 * 32];    // [buf][piece][d][32]
    __shared__ float Ps[2 * 32 * 68];           // [buf][row][68]  (68 keeps v4f 16B-aligned)
    __shared__ float redm[128], reds[128];
    const int t = threadIdx.x;
    const int w = t >> 6, l = t & 63;
    const int q4 = l >> 4, c0 = l & 15;
    const int wg = w >> 2, wl = w & 3;          // row-group / col-group
    const int mt = blockIdx.x, bh = blockIdx.y;
    const size_t qkbase = (size_t)bh * N_ * D_;
    const size_t vtbase = (size_t)bh * D_ * N_;
    // staging decomposition: 512 thr x 16B = 8KB buffer = [piece][64 rows][32 halfs]
    const int sp  = t >> 8;
    const int srw = (t >> 2) & 63;
    const int sc8 = (t & 3) * 8;

    // prologue: stage Qs (4KB, waves 0-3) + Ks chunk 0 into buf0
    if (t < 256) {
        const int qp = t >> 7, qr = (t >> 2) & 31;
        gload_lds16(&qh[qkbase + (size_t)(mt * 32 + qr) * D_ + qp * 32 + sc8], &Qs[t * 8]);
    }
    gload_lds16(&kh[qkbase + (size_t)srw * D_ + sp * 32 + sc8], &Ks[t * 8]);
    __syncthreads();

    const v8h a0 = *(const v8h*)&Qs[(wg * 16 + c0) * 32 + q4 * 8];
    const v8h a1 = *(const v8h*)&Qs[1024 + (wg * 16 + c0) * 32 + q4 * 8];

    v4f S[16];
    #pragma unroll
    for (int i = 0; i < 16; ++i) S[i] = (v4f){0.f, 0.f, 0.f, 0.f};

    // ---- QK^T: 16 chunks of 64 K-rows, stage-at-top, one barrier per chunk ----
    #pragma unroll
    for (int c = 0; c < 16; ++c) {
        const int kb = c & 1;
        if (c < 15)
            gload_lds16(&kh[qkbase + (size_t)((c + 1) * 64 + srw) * D_ + sp * 32 + sc8],
                        &Ks[(kb ^ 1) * 4096 + t * 8]);
        const int roff = (wl * 16 + c0) * 32 + q4 * 8;
        const v8h b0 = *(const v8h*)&Ks[kb * 4096 + roff];
        const v8h b1 = *(const v8h*)&Ks[kb * 4096 + 2048 + roff];
        S[c] = __builtin_amdgcn_mfma_f32_16x16x32_f16(a0, b0, S[c], 0, 0, 0);
        S[c] = __builtin_amdgcn_mfma_f32_16x16x32_f16(a1, b1, S[c], 0, 0, 0);
        if (c < 15) __syncthreads();
    }

    // ---- softmax (fp32): rows are (wg*16 + q4*4 + r), cols reduce over c0 & wl ----
    float mrow[4] = {-1e30f, -1e30f, -1e30f, -1e30f};
    #pragma unroll
    for (int kt = 0; kt < 16; ++kt)
        #pragma unroll
        for (int r = 0; r < 4; ++r) mrow[r] = fmaxf(mrow[r], S[kt][r]);
    #pragma unroll
    for (int r = 0; r < 4; ++r) {
        #pragma unroll
        for (int mask = 8; mask; mask >>= 1)
            mrow[r] = fmaxf(mrow[r], __shfl_xor(mrow[r], mask, 16));
    }
    if (c0 == 0) {
        #pragma unroll
        for (int r = 0; r < 4; ++r) redm[w * 16 + q4 * 4 + r] = mrow[r];
    }
    __syncthreads();
    // stage V slab 0 now: drains at the reds barrier -> hides under exp pass
    gload_lds16(&vth[vtbase + (size_t)srw * N_ + sp * 32 + sc8], &Vt[t * 8]);
    #pragma unroll
    for (int r = 0; r < 4; ++r) {
        const int base = wg * 64 + q4 * 4 + r;
        mrow[r] = fmaxf(fmaxf(redm[base], redm[base + 16]),
                        fmaxf(redm[base + 32], redm[base + 48]));
    }
    float srow[4] = {0.f, 0.f, 0.f, 0.f};
    #pragma unroll
    for (int kt = 0; kt < 16; ++kt)
        #pragma unroll
        for (int r = 0; r < 4; ++r) {
            const float e = __expf((S[kt][r] - mrow[r]) * SCALE_);
            S[kt][r] = e;
            srow[r] += e;
        }
    #pragma unroll
    for (int r = 0; r < 4; ++r) {
        #pragma unroll
        for (int mask = 8; mask; mask >>= 1) srow[r] += __shfl_xor(srow[r], mask, 16);
    }
    if (c0 == 0) {
        #pragma unroll
        for (int r = 0; r < 4; ++r) reds[w * 16 + q4 * 4 + r] = srow[r];
    }
    __syncthreads();
    float inv[4];
    #pragma unroll
    for (int r = 0; r < 4; ++r) {
        const int base = wg * 64 + q4 * 4 + r;
        inv[r] = 1.0f / (reds[base] + reds[base + 16] + reds[base + 32] + reds[base + 48]);
    }
    // write Ps slab 0 (buf 0)
    #pragma unroll
    for (int r = 0; r < 4; ++r)
        Ps[(wg * 16 + q4 * 4 + r) * 68 + wl * 16 + c0] = S[0][r] * inv[r];
    __syncthreads();   // drains Vt[0] stage + Ps[0] writes

    // ---- PV + attn store: 16 slabs of 64 cols, dbuf Ps/Vt, 1 barrier/slab ----
    v4f O = {0.f, 0.f, 0.f, 0.f};
    const int arow = t >> 4, acol = (t & 15) * 4;
    float* attn_base = &attn[((size_t)bh * N_ + mt * 32 + arow) * N_ + acol];
    #pragma unroll
    for (int s = 0; s < 16; ++s) {
        const int pb = s & 1;
        if (s < 15) {
            const int nb = pb ^ 1;
            #pragma unroll
            for (int r = 0; r < 4; ++r)
                Ps[nb * 2176 + (wg * 16 + q4 * 4 + r) * 68 + wl * 16 + c0] = S[s + 1][r] * inv[r];
            gload_lds16(&vth[vtbase + (size_t)srw * N_ + (s + 1) * 64 + sp * 32 + sc8],
                        &Vt[nb * 4096 + t * 8]);
        }
        // coalesced nontemporal attn store (from Ps[pb])
        {
            const v4f pv = *(const v4f*)&Ps[pb * 2176 + arow * 68 + acol];
            __builtin_nontemporal_store(pv, (v4f*)(attn_base + s * 64));
        }
        // P (A-frag, cvt fp16) x Vt (B-frag) -> O
        #pragma unroll
        for (int kk = 0; kk < 2; ++kk) {
            const float* pp = &Ps[pb * 2176 + (wg * 16 + c0) * 68 + kk * 32 + q4 * 8];
            const v4f p0 = *(const v4f*)pp;
            const v4f p1 = *(const v4f*)(pp + 4);
            v8h af;
            af[0] = (_Float16)p0[0]; af[1] = (_Float16)p0[1];
            af[2] = (_Float16)p0[2]; af[3] = (_Float16)p0[3];
            af[4] = (_Float16)p1[0]; af[5] = (_Float16)p1[1];
            af[6] = (_Float16)p1[2]; af[7] = (_Float16)p1[3];
            const v8h bf = *(const v8h*)&Vt[pb * 4096 + kk * 2048 + (wl * 16 + c0) * 32 + q4 * 8];
            O = __builtin_amdgcn_mfma_f32_16x16x32_f16(af, bf, O, 0, 0, 0);
        }
        if (s < 15) __syncthreads();
    }
    const int b = bh / H_, h = bh % H_;
    #pragma unroll
    for (int r = 0; r < 4; ++r)
        oah[((size_t)b * N_ + mt * 32 + wg * 16 + q4 * 4 + r) * C_ + h * D_ + wl * 16 + c0] =
            (_Float16)O[r];
}

// ---------------------------------------------------------------------------
// K4: out = oah[8192,768] @ wph[768,768]^T + bias, fp32 out (nontemporal).
// Same dbuf single-barrier core as K1.
// ---------------------------------------------------------------------------
__global__ __launch_bounds__(256) void gemm_proj(const _Float16* __restrict__ X,
                                                 const _Float16* __restrict__ W,
                                                 const float* __restrict__ Bias,
                                                 float* __restrict__ out) {
    __shared__ _Float16 As[2 * 128 * 32];
    __shared__ _Float16 Bs[2 * 128 * 32];
    const int t = threadIdx.x;
    const int w = t >> 6, l = t & 63;
    const int q4 = l >> 4, c0 = l & 15;
    const int wm = w & 1, wn = w >> 1;
    const int m0 = blockIdx.x * 128, n0 = blockIdx.y * 128;
    const int sc8 = (t & 3) * 8;
    const int srow = t >> 2;
    v4f acc[4][4] = {};
    #pragma unroll
    for (int i = 0; i < 2; ++i) {
        const int row = i * 64 + srow;
        gload_lds16(&X[(size_t)(m0 + row) * C_ + sc8], &As[(i * 256 + t) * 8]);
        gload_lds16(&W[(size_t)(n0 + row) * C_ + sc8], &Bs[(i * 256 + t) * 8]);
    }
    __syncthreads();
    int cb = 0;
    for (int k0 = 0; k0 < C_; k0 += 32, cb ^= 1) {
        if (k0 + 32 < C_) {
            const int nb = cb ^ 1;
            #pragma unroll
            for (int i = 0; i < 2; ++i) {
                const int row = i * 64 + srow;
                gload_lds16(&X[(size_t)(m0 + row) * C_ + k0 + 32 + sc8],
                            &As[(nb * 512 + i * 256 + t) * 8]);
                gload_lds16(&W[(size_t)(n0 + row) * C_ + k0 + 32 + sc8],
                            &Bs[(nb * 512 + i * 256 + t) * 8]);
            }
        }
        v8h a[4], b[4];
        #pragma unroll
        for (int mi = 0; mi < 4; ++mi)
            a[mi] = *(const v8h*)&As[cb * 4096 + (wm * 64 + mi * 16 + c0) * 32 + q4 * 8];
        #pragma unroll
        for (int ni = 0; ni < 4; ++ni)
            b[ni] = *(const v8h*)&Bs[cb * 4096 + (wn * 64 + ni * 16 + c0) * 32 + q4 * 8];
        #pragma unroll
        for (int mi = 0; mi < 4; ++mi)
            #pragma unroll
            for (int ni = 0; ni < 4; ++ni)
                acc[mi][ni] = __builtin_amdgcn_mfma_f32_16x16x32_f16(a[mi], b[ni], acc[mi][ni], 0, 0, 0);
        __syncthreads();
    }
    #pragma unroll
    for (int ni = 0; ni < 4; ++ni) {
        const int n = n0 + wn * 64 + ni * 16 + c0;
        const float bias = Bias[n];
        #pragma unroll
        for (int mi = 0; mi < 4; ++mi) {
            #pragma unroll
            for (int r = 0; r < 4; ++r) {
                const int m = m0 + wm * 64 + mi * 16 + q4 * 4 + r;
                __builtin_nontemporal_store(acc[mi][ni][r] + bias, &out[(size_t)m * C_ + n]);
            }
        }
    }
}

extern "C" void kernel_launch(void* const* d_in, const int* in_sizes, int n_in,
                              void* d_out, int out_size, void* d_ws, size_t ws_size,
                              hipStream_t stream) {
    const float* x      = (const float*)d_in[0];
    const float* w_qkv  = (const float*)d_in[1];
    const float* w_proj = (const float*)d_in[2];
    const float* b_proj = (const float*)d_in[3];

    float* out  = (float*)d_out;                 // [8,1024,768]
    float* attn = out + (size_t)B_ * N_ * C_;    // [8,12,1024,1024]

    const size_t NX  = (size_t)B_ * N_ * C_;     // 6,291,456
    const size_t NWQ = (size_t)3 * C_ * C_;      // 1,769,472
    const size_t NWP = (size_t)C_ * C_;          //   589,824
    _Float16* xh  = (_Float16*)d_ws;
    _Float16* wqh = xh + NX;
    _Float16* wph = wqh + NWQ;
    _Float16* qh  = wph + NWP;
    _Float16* kh  = qh + NX;
    _Float16* vth = kh + NX;
    _Float16* oah = vth + NX;

    cast_f2h<<<dim3((int)(NX / 8 / 256)), 256, 0, stream>>>(x, xh, (int)(NX / 8));
    cast_f2h<<<dim3((int)(NWQ / 8 / 256)), 256, 0, stream>>>(w_qkv, wqh, (int)(NWQ / 8));
    cast_f2h<<<dim3((int)(NWP / 8 / 256)), 256, 0, stream>>>(w_proj, wph, (int)(NWP / 8));

    gemm_qkv  <<<dim3(64, 18), 256, 0, stream>>>(xh, wqh, qh, kh, vth);
    attn_fused<<<dim3(32, 96), 512, 0, stream>>>(qh, kh, vth, attn, oah);
    gemm_proj <<<dim3(64, 6), 256, 0, stream>>>(oah, wph, b_proj, out);
}

// Round 2
// 563.477 us; speedup vs baseline: 1.1983x; 1.0256x over previous
//
#include <hip/hip_runtime.h>

#define B_ 8
#define N_ 1024
#define C_ 768
#define H_ 12
#define D_ 64
#define SCALE_ 0.125f

typedef _Float16 v8h __attribute__((ext_vector_type(8)));
typedef float v4f __attribute__((ext_vector_type(4)));

__device__ __forceinline__ void gload_lds16(const void* g, void* l) {
    __builtin_amdgcn_global_load_lds((const __attribute__((address_space(1))) void*)g,
                                     (__attribute__((address_space(3))) void*)l, 16, 0, 0);
}

// raw workgroup barrier with scheduling fences on both sides (no vmcnt drain!)
__device__ __forceinline__ void raw_sync() {
    __builtin_amdgcn_sched_barrier(0);
    __builtin_amdgcn_s_barrier();
    __builtin_amdgcn_sched_barrier(0);
}
__device__ __forceinline__ void lgkm0() {
    asm volatile("s_waitcnt lgkmcnt(0)" ::: "memory");
    __builtin_amdgcn_sched_barrier(0);
}

// ---------------------------------------------------------------------------
// cast fp32 -> fp16, 8 elems/thread
// ---------------------------------------------------------------------------
__global__ __launch_bounds__(256) void cast_f2h(const float* __restrict__ src,
                                                _Float16* __restrict__ dst, int n8) {
    const int i = blockIdx.x * 256 + threadIdx.x;
    if (i < n8) {
        const v4f a = *(const v4f*)&src[(size_t)i * 8];
        const v4f b = *(const v4f*)&src[(size_t)i * 8 + 4];
        v8h o;
        o[0] = (_Float16)a[0]; o[1] = (_Float16)a[1]; o[2] = (_Float16)a[2]; o[3] = (_Float16)a[3];
        o[4] = (_Float16)b[0]; o[5] = (_Float16)b[1]; o[6] = (_Float16)b[2]; o[7] = (_Float16)b[3];
        *(v8h*)&dst[(size_t)i * 8] = o;
    }
}

// ---------------------------------------------------------------------------
// K1: qkv = xh[8192,768] @ wqh[2304,768]^T via MFMA. 128x128 tile, BK=32,
// double-buffered LDS, single barrier per K-step. (unchanged this round)
// ---------------------------------------------------------------------------
__global__ __launch_bounds__(256) void gemm_qkv(const _Float16* __restrict__ X,
                                                const _Float16* __restrict__ W,
                                                _Float16* __restrict__ qh,
                                                _Float16* __restrict__ kh,
                                                _Float16* __restrict__ vth) {
    __shared__ _Float16 As[2 * 128 * 32];
    __shared__ _Float16 Bs[2 * 128 * 32];
    const int t = threadIdx.x;
    const int w = t >> 6, l = t & 63;
    const int q4 = l >> 4, c0 = l & 15;
    const int wm = w & 1, wn = w >> 1;
    const int m0 = blockIdx.x * 128, n0 = blockIdx.y * 128;
    const int sc8 = (t & 3) * 8;
    const int srow = t >> 2;
    v4f acc[4][4] = {};
    #pragma unroll
    for (int i = 0; i < 2; ++i) {
        const int row = i * 64 + srow;
        gload_lds16(&X[(size_t)(m0 + row) * C_ + sc8], &As[(i * 256 + t) * 8]);
        gload_lds16(&W[(size_t)(n0 + row) * C_ + sc8], &Bs[(i * 256 + t) * 8]);
    }
    __syncthreads();
    int cb = 0;
    for (int k0 = 0; k0 < C_; k0 += 32, cb ^= 1) {
        if (k0 + 32 < C_) {
            const int nb = cb ^ 1;
            #pragma unroll
            for (int i = 0; i < 2; ++i) {
                const int row = i * 64 + srow;
                gload_lds16(&X[(size_t)(m0 + row) * C_ + k0 + 32 + sc8],
                            &As[(nb * 512 + i * 256 + t) * 8]);
                gload_lds16(&W[(size_t)(n0 + row) * C_ + k0 + 32 + sc8],
                            &Bs[(nb * 512 + i * 256 + t) * 8]);
            }
        }
        v8h a[4], b[4];
        #pragma unroll
        for (int mi = 0; mi < 4; ++mi)
            a[mi] = *(const v8h*)&As[cb * 4096 + (wm * 64 + mi * 16 + c0) * 32 + q4 * 8];
        #pragma unroll
        for (int ni = 0; ni < 4; ++ni)
            b[ni] = *(const v8h*)&Bs[cb * 4096 + (wn * 64 + ni * 16 + c0) * 32 + q4 * 8];
        #pragma unroll
        for (int mi = 0; mi < 4; ++mi)
            #pragma unroll
            for (int ni = 0; ni < 4; ++ni)
                acc[mi][ni] = __builtin_amdgcn_mfma_f32_16x16x32_f16(a[mi], b[ni], acc[mi][ni], 0, 0, 0);
        __syncthreads();
    }
    const int which = n0 / C_;
    const int nbase = n0 % C_;
    #pragma unroll
    for (int ni = 0; ni < 4; ++ni) {
        const int n = nbase + wn * 64 + ni * 16 + c0;
        const int h = n >> 6, d = n & 63;
        #pragma unroll
        for (int mi = 0; mi < 4; ++mi) {
            #pragma unroll
            for (int r = 0; r < 4; ++r) {
                const int m = m0 + wm * 64 + mi * 16 + q4 * 4 + r;
                const int b = m >> 10, nn = m & 1023;
                const _Float16 val = (_Float16)acc[mi][ni][r];
                if (which == 0)
                    qh[((size_t)(b * H_ + h) * N_ + nn) * D_ + d] = val;
                else if (which == 1)
                    kh[((size_t)(b * H_ + h) * N_ + nn) * D_ + d] = val;
                else
                    vth[((size_t)(b * H_ + h) * D_ + d) * N_ + nn] = val;
            }
        }
    }
}

// ---------------------------------------------------------------------------
// K2: fused attention, counted-vmcnt pipeline (T3+T4).
// Block = 32 q-rows x one (b,h). Grid (32, 96), 512 thr = 8 waves (2 wg x 4 wl).
// Q in registers. K: 3-buffer LDS, prefetch distance 2, raw barrier + vmcnt(1)
// per chunk (vmcnt(0) only at last). PV: 3-buffer Vt (vmcnt(2) steady -- counts
// the interleaved nontemporal attn stores), double-buffered Ps with
// lgkmcnt(0)-before-barrier handoff. V0/V1 prefetch hides under softmax exp.
// ---------------------------------------------------------------------------
__global__ __launch_bounds__(512, 4) void attn_fused(const _Float16* __restrict__ qh,
                                                     const _Float16* __restrict__ kh,
                                                     const _Float16* __restrict__ vth,
                                                     float* __restrict__ attn,
                                                     _Float16* __restrict__ oah) {
    __shared__ _Float16 Ks[3 * 2 * 64 * 32];    // [buf][piece][row][32]  24KB
    __shared__ _Float16 Vt[3 * 2 * 64 * 32];    // [buf][piece][d][32]    24KB
    __shared__ float Ps[2 * 32 * 68];           // [buf][row][68]        17.4KB
    __shared__ float redm[128], reds[128];
    const int t = threadIdx.x;
    const int w = t >> 6, l = t & 63;
    const int q4 = l >> 4, c0 = l & 15;
    const int wg = w >> 2, wl = w & 3;
    const int mt = blockIdx.x, bh = blockIdx.y;
    const size_t qkbase = (size_t)bh * N_ * D_;
    const size_t vtbase = (size_t)bh * D_ * N_;
    // staging decomposition: 512 thr x 16B = 8KB = [piece][64 rows][32 halfs]
    const int sp  = t >> 8;
    const int srw = (t >> 2) & 63;
    const int sc8 = (t & 3) * 8;

    // Q fragments straight to registers (A-frags for both 32-col halves of D)
    const _Float16* qp = &qh[qkbase + (size_t)(mt * 32 + wg * 16 + c0) * D_ + q4 * 8];
    const v8h a0 = *(const v8h*)qp;
    const v8h a1 = *(const v8h*)(qp + 32);

    // prologue: K chunks 0,1 in flight
    gload_lds16(&kh[qkbase + (size_t)srw * D_ + sp * 32 + sc8], &Ks[t * 8]);
    gload_lds16(&kh[qkbase + (size_t)(64 + srw) * D_ + sp * 32 + sc8], &Ks[4096 + t * 8]);

    v4f S[16];
    #pragma unroll
    for (int i = 0; i < 16; ++i) S[i] = (v4f){0.f, 0.f, 0.f, 0.f};

    // ---- QK^T: 16 chunks of 64 K-rows, counted vmcnt, 1 raw barrier/chunk ----
    #pragma unroll
    for (int c = 0; c < 16; ++c) {
        if (c == 15) asm volatile("s_waitcnt vmcnt(0)" ::: "memory");
        else         asm volatile("s_waitcnt vmcnt(1)" ::: "memory");
        raw_sync();
        const int kb = (c % 3) * 4096;
        const int roff = (wl * 16 + c0) * 32 + q4 * 8;
        const v8h b0 = *(const v8h*)&Ks[kb + roff];
        const v8h b1 = *(const v8h*)&Ks[kb + 2048 + roff];
        S[c] = __builtin_amdgcn_mfma_f32_16x16x32_f16(a0, b0, S[c], 0, 0, 0);
        S[c] = __builtin_amdgcn_mfma_f32_16x16x32_f16(a1, b1, S[c], 0, 0, 0);
        if (c + 2 < 16)
            gload_lds16(&kh[qkbase + (size_t)((c + 2) * 64 + srw) * D_ + sp * 32 + sc8],
                        &Ks[((c + 2) % 3) * 4096 + t * 8]);
        lgkm0();   // drain our b0/b1 reads before next barrier (buffer reuse safety)
    }

    // ---- softmax (fp32) ----
    float mrow[4] = {-1e30f, -1e30f, -1e30f, -1e30f};
    #pragma unroll
    for (int kt = 0; kt < 16; ++kt)
        #pragma unroll
        for (int r = 0; r < 4; ++r) mrow[r] = fmaxf(mrow[r], S[kt][r]);
    #pragma unroll
    for (int r = 0; r < 4; ++r) {
        #pragma unroll
        for (int mask = 8; mask; mask >>= 1)
            mrow[r] = fmaxf(mrow[r], __shfl_xor(mrow[r], mask, 16));
    }
    if (c0 == 0) {
        #pragma unroll
        for (int r = 0; r < 4; ++r) redm[w * 16 + q4 * 4 + r] = mrow[r];
    }
    lgkm0();
    raw_sync();
    // prefetch V slabs 0,1 now -- they fly under the exp pass + reductions
    gload_lds16(&vth[vtbase + (size_t)srw * N_ + sp * 32 + sc8], &Vt[t * 8]);
    gload_lds16(&vth[vtbase + (size_t)srw * N_ + 64 + sp * 32 + sc8], &Vt[4096 + t * 8]);
    #pragma unroll
    for (int r = 0; r < 4; ++r) {
        const int base = wg * 64 + q4 * 4 + r;
        mrow[r] = fmaxf(fmaxf(redm[base], redm[base + 16]),
                        fmaxf(redm[base + 32], redm[base + 48]));
    }
    float srow[4] = {0.f, 0.f, 0.f, 0.f};
    #pragma unroll
    for (int kt = 0; kt < 16; ++kt)
        #pragma unroll
        for (int r = 0; r < 4; ++r) {
            const float e = __expf((S[kt][r] - mrow[r]) * SCALE_);
            S[kt][r] = e;
            srow[r] += e;
        }
    #pragma unroll
    for (int r = 0; r < 4; ++r) {
        #pragma unroll
        for (int mask = 8; mask; mask >>= 1) srow[r] += __shfl_xor(srow[r], mask, 16);
    }
    if (c0 == 0) {
        #pragma unroll
        for (int r = 0; r < 4; ++r) reds[w * 16 + q4 * 4 + r] = srow[r];
    }
    lgkm0();
    raw_sync();
    float inv[4];
    #pragma unroll
    for (int r = 0; r < 4; ++r) {
        const int base = wg * 64 + q4 * 4 + r;
        inv[r] = 1.0f / (reds[base] + reds[base + 16] + reds[base + 32] + reds[base + 48]);
    }
    // Ps slab 0 (buf 0)
    #pragma unroll
    for (int r = 0; r < 4; ++r)
        Ps[(wg * 16 + q4 * 4 + r) * 68 + wl * 16 + c0] = S[0][r] * inv[r];
    lgkm0();
    // NOTE: no barrier here -- the PV loop's iter-0 barrier is the handoff.

    // ---- PV + attn store: 16 slabs of 64 cols ----
    v4f O = {0.f, 0.f, 0.f, 0.f};
    const int arow = t >> 4, acol = (t & 15) * 4;
    float* attn_base = &attn[((size_t)bh * N_ + mt * 32 + arow) * N_ + acol];
    const int afrow = (wg * 16 + c0) * 68;
    #pragma unroll
    for (int s = 0; s < 16; ++s) {
        if (s == 0 || s == 15) asm volatile("s_waitcnt vmcnt(1)" ::: "memory");
        else                   asm volatile("s_waitcnt vmcnt(2)" ::: "memory");
        raw_sync();
        const int pb = (s & 1) * 2176;
        // coalesced nontemporal attn store
        const v4f pv = *(const v4f*)&Ps[pb + arow * 68 + acol];
        __builtin_nontemporal_store(pv, (v4f*)(attn_base + s * 64));
        // P (A-frag, cvt fp16) x Vt (B-frag) -> O
        const int vb = (s % 3) * 4096;
        #pragma unroll
        for (int kk = 0; kk < 2; ++kk) {
            const float* pp = &Ps[pb + afrow + kk * 32 + q4 * 8];
            const v4f p0 = *(const v4f*)pp;
            const v4f p1 = *(const v4f*)(pp + 4);
            v8h af;
            af[0] = (_Float16)p0[0]; af[1] = (_Float16)p0[1];
            af[2] = (_Float16)p0[2]; af[3] = (_Float16)p0[3];
            af[4] = (_Float16)p1[0]; af[5] = (_Float16)p1[1];
            af[6] = (_Float16)p1[2]; af[7] = (_Float16)p1[3];
            const v8h bf = *(const v8h*)&Vt[vb + kk * 2048 + (wl * 16 + c0) * 32 + q4 * 8];
            O = __builtin_amdgcn_mfma_f32_16x16x32_f16(af, bf, O, 0, 0, 0);
        }
        if (s < 15) {
            #pragma unroll
            for (int r = 0; r < 4; ++r)
                Ps[(pb ^ 2176) + (wg * 16 + q4 * 4 + r) * 68 + wl * 16 + c0] = S[s + 1][r] * inv[r];
            if (s + 2 < 16)
                gload_lds16(&vth[vtbase + (size_t)srw * N_ + (s + 2) * 64 + sp * 32 + sc8],
                            &Vt[((s + 2) % 3) * 4096 + t * 8]);
        }
        lgkm0();   // drain Ps writes + our Ps/Vt reads before next barrier
    }
    const int b = bh / H_, h = bh % H_;
    #pragma unroll
    for (int r = 0; r < 4; ++r)
        oah[((size_t)b * N_ + mt * 32 + wg * 16 + q4 * 4 + r) * C_ + h * D_ + wl * 16 + c0] =
            (_Float16)O[r];
}

// ---------------------------------------------------------------------------
// K4: out = oah[8192,768] @ wph[768,768]^T + bias, fp32 out (nontemporal).
// (unchanged this round)
// ---------------------------------------------------------------------------
__global__ __launch_bounds__(256) void gemm_proj(const _Float16* __restrict__ X,
                                                 const _Float16* __restrict__ W,
                                                 const float* __restrict__ Bias,
                                                 float* __restrict__ out) {
    __shared__ _Float16 As[2 * 128 * 32];
    __shared__ _Float16 Bs[2 * 128 * 32];
    const int t = threadIdx.x;
    const int w = t >> 6, l = t & 63;
    const int q4 = l >> 4, c0 = l & 15;
    const int wm = w & 1, wn = w >> 1;
    const int m0 = blockIdx.x * 128, n0 = blockIdx.y * 128;
    const int sc8 = (t & 3) * 8;
    const int srow = t >> 2;
    v4f acc[4][4] = {};
    #pragma unroll
    for (int i = 0; i < 2; ++i) {
        const int row = i * 64 + srow;
        gload_lds16(&X[(size_t)(m0 + row) * C_ + sc8], &As[(i * 256 + t) * 8]);
        gload_lds16(&W[(size_t)(n0 + row) * C_ + sc8], &Bs[(i * 256 + t) * 8]);
    }
    __syncthreads();
    int cb = 0;
    for (int k0 = 0; k0 < C_; k0 += 32, cb ^= 1) {
        if (k0 + 32 < C_) {
            const int nb = cb ^ 1;
            #pragma unroll
            for (int i = 0; i < 2; ++i) {
                const int row = i * 64 + srow;
                gload_lds16(&X[(size_t)(m0 + row) * C_ + k0 + 32 + sc8],
                            &As[(nb * 512 + i * 256 + t) * 8]);
                gload_lds16(&W[(size_t)(n0 + row) * C_ + k0 + 32 + sc8],
                            &Bs[(nb * 512 + i * 256 + t) * 8]);
            }
        }
        v8h a[4], b[4];
        #pragma unroll
        for (int mi = 0; mi < 4; ++mi)
            a[mi] = *(const v8h*)&As[cb * 4096 + (wm * 64 + mi * 16 + c0) * 32 + q4 * 8];
        #pragma unroll
        for (int ni = 0; ni < 4; ++ni)
            b[ni] = *(const v8h*)&Bs[cb * 4096 + (wn * 64 + ni * 16 + c0) * 32 + q4 * 8];
        #pragma unroll
        for (int mi = 0; mi < 4; ++mi)
            #pragma unroll
            for (int ni = 0; ni < 4; ++ni)
                acc[mi][ni] = __builtin_amdgcn_mfma_f32_16x16x32_f16(a[mi], b[ni], acc[mi][ni], 0, 0, 0);
        __syncthreads();
    }
    #pragma unroll
    for (int ni = 0; ni < 4; ++ni) {
        const int n = n0 + wn * 64 + ni * 16 + c0;
        const float bias = Bias[n];
        #pragma unroll
        for (int mi = 0; mi < 4; ++mi) {
            #pragma unroll
            for (int r = 0; r < 4; ++r) {
                const int m = m0 + wm * 64 + mi * 16 + q4 * 4 + r;
                __builtin_nontemporal_store(acc[mi][ni][r] + bias, &out[(size_t)m * C_ + n]);
            }
        }
    }
}

extern "C" void kernel_launch(void* const* d_in, const int* in_sizes, int n_in,
                              void* d_out, int out_size, void* d_ws, size_t ws_size,
                              hipStream_t stream) {
    const float* x      = (const float*)d_in[0];
    const float* w_qkv  = (const float*)d_in[1];
    const float* w_proj = (const float*)d_in[2];
    const float* b_proj = (const float*)d_in[3];

    float* out  = (float*)d_out;                 // [8,1024,768]
    float* attn = out + (size_t)B_ * N_ * C_;    // [8,12,1024,1024]

    const size_t NX  = (size_t)B_ * N_ * C_;
    const size_t NWQ = (size_t)3 * C_ * C_;
    const size_t NWP = (size_t)C_ * C_;
    _Float16* xh  = (_Float16*)d_ws;
    _Float16* wqh = xh + NX;
    _Float16* wph = wqh + NWQ;
    _Float16* qh  = wph + NWP;
    _Float16* kh  = qh + NX;
    _Float16* vth = kh + NX;
    _Float16* oah = vth + NX;

    cast_f2h<<<dim3((int)(NX / 8 / 256)), 256, 0, stream>>>(x, xh, (int)(NX / 8));
    cast_f2h<<<dim3((int)(NWQ / 8 / 256)), 256, 0, stream>>>(w_qkv, wqh, (int)(NWQ / 8));
    cast_f2h<<<dim3((int)(NWP / 8 / 256)), 256, 0, stream>>>(w_proj, wph, (int)(NWP / 8));

    gemm_qkv  <<<dim3(64, 18), 256, 0, stream>>>(xh, wqh, qh, kh, vth);
    attn_fused<<<dim3(32, 96), 512, 0, stream>>>(qh, kh, vth, attn, oah);
    gemm_proj <<<dim3(64, 6), 256, 0, stream>>>(oah, wph, b_proj, out);
}